// Round 7
// baseline (1961.526 us; speedup 1.0000x reference)
//
#include <hip/hip_runtime.h>
#include <math.h>

#define NTHR  256
#define SCTH  1024

static __device__ __forceinline__ float sigf(float x) {
  return 1.0f / (1.0f + __expf(-x));
}
static __device__ __forceinline__ float tanhfast(float x) {
  return 2.0f / (1.0f + __expf(-2.0f * x)) - 1.0f;
}

// m = x @ conv_weight   (x:[N,4], w:[4,4] row-major, m:[N,4])
__global__ void conv_m_kernel(const float* __restrict__ x,
                              const float* __restrict__ w,
                              float* __restrict__ m, int n) {
  int i = blockIdx.x * blockDim.x + threadIdx.x;
  if (i >= n) return;
  float4 xv = reinterpret_cast<const float4*>(x)[i];
  float4 mv;
  mv.x = xv.x * w[0] + xv.y * w[4] + xv.z * w[8]  + xv.w * w[12];
  mv.y = xv.x * w[1] + xv.y * w[5] + xv.z * w[9]  + xv.w * w[13];
  mv.z = xv.x * w[2] + xv.y * w[6] + xv.z * w[10] + xv.w * w[14];
  mv.w = xv.x * w[3] + xv.y * w[7] + xv.z * w[11] + xv.w * w[15];
  reinterpret_cast<float4*>(m)[i] = mv;
}

// ---------- full-CSR fast path (no LDS atomics in hot loops) ----------

// per-node degree histogram: 1 fire-and-forget global int atomic per edge
__global__ __launch_bounds__(NTHR) void nodehist_kernel(
    const int* __restrict__ dst, int E, int* __restrict__ nodeCnt) {
  int i4 = blockIdx.x * blockDim.x + threadIdx.x;
  int lim4 = E >> 2;
  if (i4 < lim4) {
    int4 d = reinterpret_cast<const int4*>(dst)[i4];
    atomicAdd(&nodeCnt[d.x], 1);
    atomicAdd(&nodeCnt[d.y], 1);
    atomicAdd(&nodeCnt[d.z], 1);
    atomicAdd(&nodeCnt[d.w], 1);
  }
  if (i4 == 0) {
    for (int e = E & ~3; e < E; ++e) atomicAdd(&nodeCnt[dst[e]], 1);
  }
}

// exclusive scan over n ints, 3 kernels (n <= SCTH*SCTH)
__global__ void scan1_kernel(const int* __restrict__ in, int n,
                             int* __restrict__ outExcl,
                             int* __restrict__ blockSum) {
  __shared__ int s[SCTH];
  int t = threadIdx.x, g = blockIdx.x * SCTH + t;
  int v = (g < n) ? in[g] : 0;
  s[t] = v;
  __syncthreads();
  for (int off = 1; off < SCTH; off <<= 1) {
    int u = (t >= off) ? s[t - off] : 0;
    __syncthreads();
    s[t] += u;
    __syncthreads();
  }
  if (g < n) outExcl[g] = s[t] - v;
  if (t == SCTH - 1) blockSum[blockIdx.x] = s[t];
}

__global__ void scan2_kernel(const int* __restrict__ blockSum, int nb,
                             int* __restrict__ blockOff) {
  __shared__ int s[SCTH];
  int t = threadIdx.x;
  int v = (t < nb) ? blockSum[t] : 0;
  s[t] = v;
  __syncthreads();
  for (int off = 1; off < SCTH; off <<= 1) {
    int u = (t >= off) ? s[t - off] : 0;
    __syncthreads();
    s[t] += u;
    __syncthreads();
  }
  if (t < nb) blockOff[t] = s[t] - v;
}

__global__ void scan3_kernel(int* __restrict__ nodeStart,
                             int* __restrict__ nodeCursor,
                             const int* __restrict__ blockOff, int n) {
  int g = blockIdx.x * SCTH + threadIdx.x;
  if (g < n) {
    int v = nodeStart[g] + blockOff[blockIdx.x];
    nodeStart[g] = v;
    nodeCursor[g] = v;
  }
}

// scatter edges into per-node runs: 1 global rtn atomic + 8B write per edge
__global__ __launch_bounds__(NTHR) void csr_scatter_kernel(
    const int* __restrict__ ei, const float* __restrict__ ew, int E,
    int* __restrict__ nodeCursor, int2* __restrict__ csr) {
  int i4 = blockIdx.x * blockDim.x + threadIdx.x;
  int lim4 = E >> 2;
  if (i4 < lim4) {
    int4 s = reinterpret_cast<const int4*>(ei)[i4];
    int4 d = reinterpret_cast<const int4*>(ei + E)[i4];
    float4 w = reinterpret_cast<const float4*>(ew)[i4];
    int p0 = atomicAdd(&nodeCursor[d.x], 1);
    int p1 = atomicAdd(&nodeCursor[d.y], 1);
    int p2 = atomicAdd(&nodeCursor[d.z], 1);
    int p3 = atomicAdd(&nodeCursor[d.w], 1);
    csr[p0] = make_int2(s.x, __float_as_int(w.x));
    csr[p1] = make_int2(s.y, __float_as_int(w.y));
    csr[p2] = make_int2(s.z, __float_as_int(w.z));
    csr[p3] = make_int2(s.w, __float_as_int(w.w));
  }
  if (i4 == 0) {
    for (int e = E & ~3; e < E; ++e) {
      int p = atomicAdd(&nodeCursor[ei[E + e]], 1);
      csr[p] = make_int2(ei[e], __float_as_int(ew[e]));
    }
  }
}

// one thread per node: stream CSR run (register accumulate, NO atomics),
// then fused GRU + LSTM + head. Weights staged in LDS.
__global__ __launch_bounds__(NTHR) void agg_gru_lstm_kernel(
    const float* __restrict__ x, const float* __restrict__ m,
    const int2* __restrict__ csr, const int* __restrict__ nodeStart,
    const int* __restrict__ nodeCnt,
    const float* __restrict__ h0, const float* __restrict__ c0,
    const float* __restrict__ gwi, const float* __restrict__ gwh,
    const float* __restrict__ gbi, const float* __restrict__ gbh,
    const float* __restrict__ lwi, const float* __restrict__ lwh,
    const float* __restrict__ lbi, const float* __restrict__ lbh,
    const float* __restrict__ linw, const float* __restrict__ linb,
    float* __restrict__ out, float* __restrict__ hout, float* __restrict__ cout,
    int n) {
  __shared__ float4 s_lwh[1024];   // [j*8+q], j<128, q<8
  __shared__ float4 s_lwi[128];    // [j]
  __shared__ float  s_lb[128];     // lbi[j]+lbh[j]
  __shared__ float  s_linw[32];
  __shared__ float  s_gwi[48], s_gwh[48], s_gbi[12], s_gbh[12];

  int tid = threadIdx.x;
  for (int k = tid; k < 4096; k += NTHR) ((float*)s_lwh)[k] = lwh[k];
  for (int k = tid; k < 512; k += NTHR) ((float*)s_lwi)[k] = lwi[k];
  if (tid < 128) s_lb[tid] = lbi[tid] + lbh[tid];
  if (tid < 32) s_linw[tid] = linw[tid];
  if (tid < 48) { s_gwi[tid] = gwi[tid]; s_gwh[tid] = gwh[tid]; }
  if (tid < 12) { s_gbi[tid] = gbi[tid]; s_gbh[tid] = gbh[tid]; }
  __syncthreads();

  int i = blockIdx.x * blockDim.x + tid;
  if (i >= n) return;

  // ---- mean aggregation over this node's CSR run (register-only)
  const float4* m4 = reinterpret_cast<const float4*>(m);
  int p = nodeStart[i];
  int cnt = nodeCnt[i];
  int e = p + cnt;
  float ax = 0.0f, ay = 0.0f, az = 0.0f, aw = 0.0f;
  for (; p + 4 <= e; p += 4) {
    int2 r0 = csr[p], r1 = csr[p + 1], r2 = csr[p + 2], r3 = csr[p + 3];
    float4 v0 = m4[r0.x];
    float4 v1 = m4[r1.x];
    float4 v2 = m4[r2.x];
    float4 v3 = m4[r3.x];
    float w0 = __int_as_float(r0.y), w1 = __int_as_float(r1.y);
    float w2 = __int_as_float(r2.y), w3 = __int_as_float(r3.y);
    ax += v0.x * w0 + v1.x * w1 + v2.x * w2 + v3.x * w3;
    ay += v0.y * w0 + v1.y * w1 + v2.y * w2 + v3.y * w3;
    az += v0.z * w0 + v1.z * w1 + v2.z * w2 + v3.z * w3;
    aw += v0.w * w0 + v1.w * w1 + v2.w * w2 + v3.w * w3;
  }
  for (; p < e; ++p) {
    int2 r = csr[p];
    float4 v = m4[r.x];
    float w = __int_as_float(r.y);
    ax += v.x * w; ay += v.y * w; az += v.z * w; aw += v.w * w;
  }
  float inv = 1.0f / fmaxf((float)cnt, 1.0f);
  float agg[4] = {ax * inv, ay * inv, az * inv, aw * inv};

  float4 xv = reinterpret_cast<const float4*>(x)[i];
  float xa[4] = {xv.x, xv.y, xv.z, xv.w};

  // ---- GRUCell (gate order r,z,n)
  float hc[4];
#pragma unroll
  for (int c = 0; c < 4; ++c) {
    float gi_r = s_gbi[c],     gh_r = s_gbh[c];
    float gi_z = s_gbi[4 + c], gh_z = s_gbh[4 + c];
    float gi_n = s_gbi[8 + c], gh_n = s_gbh[8 + c];
#pragma unroll
    for (int k = 0; k < 4; ++k) {
      gi_r += agg[k] * s_gwi[c * 4 + k];       gh_r += xa[k] * s_gwh[c * 4 + k];
      gi_z += agg[k] * s_gwi[(4 + c) * 4 + k]; gh_z += xa[k] * s_gwh[(4 + c) * 4 + k];
      gi_n += agg[k] * s_gwi[(8 + c) * 4 + k]; gh_n += xa[k] * s_gwh[(8 + c) * 4 + k];
    }
    float r = sigf(gi_r + gh_r);
    float z = sigf(gi_z + gh_z);
    float nn = tanhfast(gi_n + r * gh_n);
    hc[c] = (1.0f - z) * nn + z * xa[c];
  }

  // ---- LSTM single step (gate order i,f,g,o)
  const float4* h04 = reinterpret_cast<const float4*>(h0) + (size_t)i * 8;
  const float4* c04 = reinterpret_cast<const float4*>(c0) + (size_t)i * 8;
  float hp[32];
#pragma unroll
  for (int q = 0; q < 8; ++q) {
    float4 hv = h04[q];
    hp[q * 4 + 0] = hv.x; hp[q * 4 + 1] = hv.y;
    hp[q * 4 + 2] = hv.z; hp[q * 4 + 3] = hv.w;
  }
  float oacc = linb[0];
  float4* hout4 = reinterpret_cast<float4*>(hout) + (size_t)i * 8;
  float4* cout4 = reinterpret_cast<float4*>(cout) + (size_t)i * 8;

#pragma unroll
  for (int jc = 0; jc < 8; ++jc) {
    float4 cpv = c04[jc];
    float cpa[4] = {cpv.x, cpv.y, cpv.z, cpv.w};
    float hn[4], cn[4];
#pragma unroll
    for (int jj = 0; jj < 4; ++jj) {
      int j = jc * 4 + jj;
      float gI = s_lb[j];
      float gF = s_lb[32 + j];
      float gG = s_lb[64 + j];
      float gO = s_lb[96 + j];
      float4 wi = s_lwi[j], wf = s_lwi[32 + j], wg = s_lwi[64 + j], wo = s_lwi[96 + j];
      gI += hc[0] * wi.x + hc[1] * wi.y + hc[2] * wi.z + hc[3] * wi.w;
      gF += hc[0] * wf.x + hc[1] * wf.y + hc[2] * wf.z + hc[3] * wf.w;
      gG += hc[0] * wg.x + hc[1] * wg.y + hc[2] * wg.z + hc[3] * wg.w;
      gO += hc[0] * wo.x + hc[1] * wo.y + hc[2] * wo.z + hc[3] * wo.w;
#pragma unroll
      for (int q = 0; q < 8; ++q) {
        float4 a = s_lwh[j * 8 + q];
        float4 b = s_lwh[(32 + j) * 8 + q];
        float4 g = s_lwh[(64 + j) * 8 + q];
        float4 o = s_lwh[(96 + j) * 8 + q];
        float p0 = hp[q * 4 + 0], p1 = hp[q * 4 + 1];
        float p2 = hp[q * 4 + 2], p3 = hp[q * 4 + 3];
        gI += p0 * a.x + p1 * a.y + p2 * a.z + p3 * a.w;
        gF += p0 * b.x + p1 * b.y + p2 * b.z + p3 * b.w;
        gG += p0 * g.x + p1 * g.y + p2 * g.z + p3 * g.w;
        gO += p0 * o.x + p1 * o.y + p2 * o.z + p3 * o.w;
      }
      float ig = sigf(gI), fg = sigf(gF), og = sigf(gO), gg = tanhfast(gG);
      float cnew = fg * cpa[jj] + ig * gg;
      float hnew = og * tanhfast(cnew);
      cn[jj] = cnew; hn[jj] = hnew;
      oacc += fmaxf(hnew, 0.0f) * s_linw[j];
    }
    hout4[jc] = make_float4(hn[0], hn[1], hn[2], hn[3]);
    cout4[jc] = make_float4(cn[0], cn[1], cn[2], cn[3]);
  }
  out[i] = oacc;
}

// ---------- fallback path (known correct, atomic-bound) ----------

__global__ void edge_kernel(const int* __restrict__ ei,
                            const float* __restrict__ ew,
                            const float* __restrict__ m,
                            float* __restrict__ summed,
                            float* __restrict__ cnt, int E) {
  int t = blockIdx.x * blockDim.x + threadIdx.x;
  int e0 = t * 4;
  const float4* m4 = reinterpret_cast<const float4*>(m);
  for (int e = e0; e < E && e < e0 + 4; ++e) {
    int s = ei[e], d = ei[E + e];
    float w = ew[e];
    float4 mv = m4[s];
    float* p = summed + 4ll * d;
    unsafeAtomicAdd(p + 0, mv.x * w);
    unsafeAtomicAdd(p + 1, mv.y * w);
    unsafeAtomicAdd(p + 2, mv.z * w);
    unsafeAtomicAdd(p + 3, mv.w * w);
    unsafeAtomicAdd(cnt + d, 1.0f);
  }
}

__global__ __launch_bounds__(NTHR) void node_kernel(
    const float* __restrict__ x, const float* __restrict__ summed,
    const float* __restrict__ cnt,
    const float* __restrict__ h0, const float* __restrict__ c0,
    const float* __restrict__ gwi, const float* __restrict__ gwh,
    const float* __restrict__ gbi, const float* __restrict__ gbh,
    const float* __restrict__ lwi, const float* __restrict__ lwh,
    const float* __restrict__ lbi, const float* __restrict__ lbh,
    const float* __restrict__ linw, const float* __restrict__ linb,
    float* __restrict__ out, float* __restrict__ hout, float* __restrict__ cout,
    int n) {
  int i = blockIdx.x * blockDim.x + threadIdx.x;
  if (i >= n) return;
  float4 sv = reinterpret_cast<const float4*>(summed)[i];
  float inv = 1.0f / fmaxf(cnt[i], 1.0f);
  float agg[4] = {sv.x * inv, sv.y * inv, sv.z * inv, sv.w * inv};
  float4 xv = reinterpret_cast<const float4*>(x)[i];
  float xa[4] = {xv.x, xv.y, xv.z, xv.w};
  float hc[4];
#pragma unroll
  for (int c = 0; c < 4; ++c) {
    float gi_r = gbi[c],     gh_r = gbh[c];
    float gi_z = gbi[4 + c], gh_z = gbh[4 + c];
    float gi_n = gbi[8 + c], gh_n = gbh[8 + c];
#pragma unroll
    for (int k = 0; k < 4; ++k) {
      gi_r += agg[k] * gwi[c * 4 + k];       gh_r += xa[k] * gwh[c * 4 + k];
      gi_z += agg[k] * gwi[(4 + c) * 4 + k]; gh_z += xa[k] * gwh[(4 + c) * 4 + k];
      gi_n += agg[k] * gwi[(8 + c) * 4 + k]; gh_n += xa[k] * gwh[(8 + c) * 4 + k];
    }
    float r = sigf(gi_r + gh_r);
    float z = sigf(gi_z + gh_z);
    float nn = tanhfast(gi_n + r * gh_n);
    hc[c] = (1.0f - z) * nn + z * xa[c];
  }
  const float4* h04 = reinterpret_cast<const float4*>(h0) + (size_t)i * 8;
  const float4* c04 = reinterpret_cast<const float4*>(c0) + (size_t)i * 8;
  float hp[32];
#pragma unroll
  for (int q = 0; q < 8; ++q) {
    float4 hv = h04[q];
    hp[q * 4 + 0] = hv.x; hp[q * 4 + 1] = hv.y;
    hp[q * 4 + 2] = hv.z; hp[q * 4 + 3] = hv.w;
  }
  const float4* wih4 = reinterpret_cast<const float4*>(lwi);
  const float4* whh4 = reinterpret_cast<const float4*>(lwh);
  float oacc = linb[0];
  float4* hout4 = reinterpret_cast<float4*>(hout) + (size_t)i * 8;
  float4* cout4 = reinterpret_cast<float4*>(cout) + (size_t)i * 8;
#pragma unroll
  for (int jc = 0; jc < 8; ++jc) {
    float4 cpv = c04[jc];
    float cpa[4] = {cpv.x, cpv.y, cpv.z, cpv.w};
    float hn[4], cn[4];
#pragma unroll
    for (int jj = 0; jj < 4; ++jj) {
      int j = jc * 4 + jj;
      float gI = lbi[j]      + lbh[j];
      float gF = lbi[32 + j] + lbh[32 + j];
      float gG = lbi[64 + j] + lbh[64 + j];
      float gO = lbi[96 + j] + lbh[96 + j];
      float4 wi = wih4[j], wf = wih4[32 + j], wg = wih4[64 + j], wo = wih4[96 + j];
      gI += hc[0] * wi.x + hc[1] * wi.y + hc[2] * wi.z + hc[3] * wi.w;
      gF += hc[0] * wf.x + hc[1] * wf.y + hc[2] * wf.z + hc[3] * wf.w;
      gG += hc[0] * wg.x + hc[1] * wg.y + hc[2] * wg.z + hc[3] * wg.w;
      gO += hc[0] * wo.x + hc[1] * wo.y + hc[2] * wo.z + hc[3] * wo.w;
#pragma unroll
      for (int q = 0; q < 8; ++q) {
        float4 a = whh4[j * 8 + q];
        float4 b = whh4[(32 + j) * 8 + q];
        float4 g = whh4[(64 + j) * 8 + q];
        float4 o = whh4[(96 + j) * 8 + q];
        float p0 = hp[q * 4 + 0], p1 = hp[q * 4 + 1];
        float p2 = hp[q * 4 + 2], p3 = hp[q * 4 + 3];
        gI += p0 * a.x + p1 * a.y + p2 * a.z + p3 * a.w;
        gF += p0 * b.x + p1 * b.y + p2 * b.z + p3 * b.w;
        gG += p0 * g.x + p1 * g.y + p2 * g.z + p3 * g.w;
        gO += p0 * o.x + p1 * o.y + p2 * o.z + p3 * o.w;
      }
      float ig = sigf(gI), fg = sigf(gF), og = sigf(gO), gg = tanhfast(gG);
      float cnew = fg * cpa[jj] + ig * gg;
      float hnew = og * tanhfast(cnew);
      cn[jj] = cnew; hn[jj] = hnew;
      oacc += fmaxf(hnew, 0.0f) * linw[j];
    }
    hout4[jc] = make_float4(hn[0], hn[1], hn[2], hn[3]);
    cout4[jc] = make_float4(cn[0], cn[1], cn[2], cn[3]);
  }
  out[i] = oacc;
}

extern "C" void kernel_launch(void* const* d_in, const int* in_sizes, int n_in,
                              void* d_out, int out_size, void* d_ws, size_t ws_size,
                              hipStream_t stream) {
  const float* x     = (const float*)d_in[0];
  const int*   ei    = (const int*)d_in[1];
  const float* ew    = (const float*)d_in[2];
  const float* h0    = (const float*)d_in[3];
  const float* c0    = (const float*)d_in[4];
  const float* convw = (const float*)d_in[5];
  const float* gwi   = (const float*)d_in[6];
  const float* gwh   = (const float*)d_in[7];
  const float* gbi   = (const float*)d_in[8];
  const float* gbh   = (const float*)d_in[9];
  const float* lwi   = (const float*)d_in[10];
  const float* lwh   = (const float*)d_in[11];
  const float* lbi   = (const float*)d_in[12];
  const float* lbh   = (const float*)d_in[13];
  const float* linw  = (const float*)d_in[14];
  const float* linb  = (const float*)d_in[15];

  int n = in_sizes[0] / 4;   // N nodes
  int E = in_sizes[1] / 2;   // edges

  float* out  = (float*)d_out;
  float* hout = out + n;
  float* cout = hout + (size_t)n * 32;

  int nbScan = (n + SCTH - 1) / SCTH;
  size_t need = (size_t)E * 8 + (size_t)n * 16 + (size_t)n * 12 +
                (size_t)SCTH * 8 + 256;

  if (nbScan <= SCTH && ws_size >= need) {
    // ---- full-CSR fast path ----
    int2*  csr      = (int2*)d_ws;                        // E records
    float* m        = (float*)(csr + E);                  // N*4
    int*   nodeCnt  = (int*)(m + (size_t)n * 4);          // N
    int*   nodeSt   = nodeCnt + n;                        // N
    int*   nodeCur  = nodeSt + n;                         // N
    int*   blockSum = nodeCur + n;                        // SCTH
    int*   blockOff = blockSum + SCTH;                    // SCTH

    hipMemsetAsync(nodeCnt, 0, (size_t)n * sizeof(int), stream);
    conv_m_kernel<<<(n + NTHR - 1) / NTHR, NTHR, 0, stream>>>(x, convw, m, n);

    int e4 = E >> 2;
    int ehBlocks = (e4 + NTHR - 1) / NTHR;
    nodehist_kernel<<<ehBlocks, NTHR, 0, stream>>>(ei + E, E, nodeCnt);
    scan1_kernel<<<nbScan, SCTH, 0, stream>>>(nodeCnt, n, nodeSt, blockSum);
    scan2_kernel<<<1, SCTH, 0, stream>>>(blockSum, nbScan, blockOff);
    scan3_kernel<<<nbScan, SCTH, 0, stream>>>(nodeSt, nodeCur, blockOff, n);
    csr_scatter_kernel<<<ehBlocks, NTHR, 0, stream>>>(ei, ew, E, nodeCur, csr);

    agg_gru_lstm_kernel<<<(n + NTHR - 1) / NTHR, NTHR, 0, stream>>>(
        x, m, csr, nodeSt, nodeCnt, h0, c0,
        gwi, gwh, gbi, gbh, lwi, lwh, lbi, lbh, linw, linb,
        out, hout, cout, n);
  } else {
    // ---- fallback: global-atomic scatter (known correct) ----
    float* m      = (float*)d_ws;
    float* summed = m + (size_t)n * 4;
    float* cntp   = summed + (size_t)n * 4;
    hipMemsetAsync(summed, 0, (size_t)n * 5 * sizeof(float), stream);
    conv_m_kernel<<<(n + NTHR - 1) / NTHR, NTHR, 0, stream>>>(x, convw, m, n);
    int et = (E + 3) / 4;
    edge_kernel<<<(et + NTHR - 1) / NTHR, NTHR, 0, stream>>>(ei, ew, m, summed, cntp, E);
    node_kernel<<<(n + NTHR - 1) / NTHR, NTHR, 0, stream>>>(
        x, summed, cntp, h0, c0,
        gwi, gwh, gbi, gbh, lwi, lwh, lbi, lbh, linw, linb,
        out, hout, cout, n);
  }
}

// Round 9
// 940.300 us; speedup vs baseline: 2.0861x; 2.0861x over previous
//
#include <hip/hip_runtime.h>
#include <math.h>

#define B_SHIFT 8          // 256 nodes per bucket
#define BMASK   255
#define CHUNK   8192       // edges per binning block
#define CITER   (CHUNK / (NTHR * 4))
#define NTHR    256
#define SEG     4          // segments per bucket in edge_agg

// native LDS fp add
#define LDSADD(p, v) __hip_atomic_fetch_add((p), (v), __ATOMIC_RELAXED, \
                                            __HIP_MEMORY_SCOPE_WORKGROUP)

static __device__ __forceinline__ float sigf(float x) {
  return 1.0f / (1.0f + __expf(-x));
}
static __device__ __forceinline__ float tanhfast(float x) {
  return 2.0f / (1.0f + __expf(-2.0f * x)) - 1.0f;
}

// m = x @ conv_weight   (x:[N,4], w:[4,4] row-major, m:[N,4])
__global__ void conv_m_kernel(const float* __restrict__ x,
                              const float* __restrict__ w,
                              float* __restrict__ m, int n) {
  int i = blockIdx.x * blockDim.x + threadIdx.x;
  if (i >= n) return;
  float4 xv = reinterpret_cast<const float4*>(x)[i];
  float4 mv;
  mv.x = xv.x * w[0] + xv.y * w[4] + xv.z * w[8]  + xv.w * w[12];
  mv.y = xv.x * w[1] + xv.y * w[5] + xv.z * w[9]  + xv.w * w[13];
  mv.z = xv.x * w[2] + xv.y * w[6] + xv.z * w[10] + xv.w * w[14];
  mv.w = xv.x * w[3] + xv.y * w[7] + xv.z * w[11] + xv.w * w[15];
  reinterpret_cast<float4*>(m)[i] = mv;
}

// ---------- fast path: bin by dst bucket, then LDS-accumulate ----------

__global__ __launch_bounds__(NTHR) void hist_kernel(const int* __restrict__ dst,
                                                    int E, int B,
                                                    int* __restrict__ gCnt) {
  __shared__ int h[1024];
  for (int b = threadIdx.x; b < B; b += NTHR) h[b] = 0;
  __syncthreads();
  const int4* d4 = reinterpret_cast<const int4*>(dst);
  int i4base = (int)(((long long)blockIdx.x * CHUNK) >> 2);
  int lim4 = E >> 2;
#pragma unroll
  for (int j = 0; j < CITER; ++j) {
    int i4 = i4base + j * NTHR + threadIdx.x;
    if (i4 < lim4) {
      int4 d = d4[i4];
      atomicAdd(&h[d.x >> B_SHIFT], 1);
      atomicAdd(&h[d.y >> B_SHIFT], 1);
      atomicAdd(&h[d.z >> B_SHIFT], 1);
      atomicAdd(&h[d.w >> B_SHIFT], 1);
    }
  }
  if (blockIdx.x == 0 && threadIdx.x == 0) {
    for (int e = E & ~3; e < E; ++e) atomicAdd(&h[dst[e] >> B_SHIFT], 1);
  }
  __syncthreads();
  for (int b = threadIdx.x; b < B; b += NTHR) {
    int c = h[b];
    if (c) atomicAdd(&gCnt[b], c);
  }
}

__global__ void scan_kernel(const int* __restrict__ gCnt, int B,
                            int* __restrict__ start, int* __restrict__ cursor) {
  __shared__ int s[1024];
  int t = threadIdx.x;
  int v = (t < B) ? gCnt[t] : 0;
  s[t] = v;
  __syncthreads();
  for (int off = 1; off < 1024; off <<= 1) {
    int u = (t >= off) ? s[t - off] : 0;
    __syncthreads();
    s[t] += u;
    __syncthreads();
  }
  if (t < B) {
    int excl = (t == 0) ? 0 : s[t - 1];
    start[t] = excl;
    cursor[t] = excl;
  }
  if (t == 0) start[B] = s[1023];
}

// scatter edges into bucket-contiguous regions: rec=(src<<8 | dst&255, w)
__global__ __launch_bounds__(NTHR) void bin_kernel(const int* __restrict__ ei,
                                                   const float* __restrict__ ew,
                                                   int E, int B,
                                                   int* __restrict__ cursor,
                                                   int2* __restrict__ binned) {
  __shared__ int h[1024];
  for (int b = threadIdx.x; b < B; b += NTHR) h[b] = 0;
  __syncthreads();
  const int* dst = ei + E;
  const int4* d4 = reinterpret_cast<const int4*>(dst);
  const int4* s4 = reinterpret_cast<const int4*>(ei);
  const float4* w4 = reinterpret_cast<const float4*>(ew);
  int i4base = (int)(((long long)blockIdx.x * CHUNK) >> 2);
  int lim4 = E >> 2;
#pragma unroll
  for (int j = 0; j < CITER; ++j) {
    int i4 = i4base + j * NTHR + threadIdx.x;
    if (i4 < lim4) {
      int4 d = d4[i4];
      atomicAdd(&h[d.x >> B_SHIFT], 1);
      atomicAdd(&h[d.y >> B_SHIFT], 1);
      atomicAdd(&h[d.z >> B_SHIFT], 1);
      atomicAdd(&h[d.w >> B_SHIFT], 1);
    }
  }
  __syncthreads();
  for (int b = threadIdx.x; b < B; b += NTHR) {
    int c = h[b];
    if (c) h[b] = atomicAdd(&cursor[b], c);
  }
  __syncthreads();
#pragma unroll
  for (int j = 0; j < CITER; ++j) {
    int i4 = i4base + j * NTHR + threadIdx.x;
    if (i4 < lim4) {
      int4 d = d4[i4];
      int4 s = s4[i4];
      float4 w = w4[i4];
      int p;
      p = atomicAdd(&h[d.x >> B_SHIFT], 1);
      binned[p] = make_int2((s.x << B_SHIFT) | (d.x & BMASK), __float_as_int(w.x));
      p = atomicAdd(&h[d.y >> B_SHIFT], 1);
      binned[p] = make_int2((s.y << B_SHIFT) | (d.y & BMASK), __float_as_int(w.y));
      p = atomicAdd(&h[d.z >> B_SHIFT], 1);
      binned[p] = make_int2((s.z << B_SHIFT) | (d.z & BMASK), __float_as_int(w.z));
      p = atomicAdd(&h[d.w >> B_SHIFT], 1);
      binned[p] = make_int2((s.w << B_SHIFT) | (d.w & BMASK), __float_as_int(w.w));
    }
  }
  if (blockIdx.x == 0 && threadIdx.x == 0) {
    for (int e = E & ~3; e < E; ++e) {
      int d = dst[e];
      int p = atomicAdd(&cursor[d >> B_SHIFT], 1);
      binned[p] = make_int2((ei[e] << B_SHIFT) | (d & BMASK), __float_as_int(ew[e]));
    }
  }
}

// grid (bucket, segment): LDS-accumulate a segment of the bucket's edges.
// Accumulator duplicated x2 by thread parity to halve same-address
// atomic serialization; copies are bank-aligned (1280 % 32 == 0) so
// cross-parity collisions are free 2-way bank aliasing.
__global__ __launch_bounds__(NTHR) void edge_agg_kernel(
    const float* __restrict__ m, const int2* __restrict__ binned,
    const int* __restrict__ start, float* __restrict__ sumBuf,
    float* __restrict__ cntBuf, int n) {
  __shared__ float acc[2][NTHR * 5];
  int tid = threadIdx.x;
  int b = blockIdx.x;
  int par = tid & 1;
  for (int k = tid; k < 2 * NTHR * 5; k += NTHR) ((float*)acc)[k] = 0.0f;
  __syncthreads();

  int s0 = start[b], e0 = start[b + 1];
  int len = e0 - s0;
  int s = s0 + (int)((long long)len * blockIdx.y / SEG);
  int e = s0 + (int)((long long)len * (blockIdx.y + 1) / SEG);

  const float4* m4 = reinterpret_cast<const float4*>(m);
  float* ac = acc[par];
  int i = s + tid;
  // 8x unroll: 8 binned loads, then 8 gathers, all in flight before LDS ops
  for (; i + 7 * NTHR < e; i += 8 * NTHR) {
    int2 r[8];
    float4 v[8];
#pragma unroll
    for (int u = 0; u < 8; ++u) r[u] = binned[i + u * NTHR];
#pragma unroll
    for (int u = 0; u < 8; ++u) v[u] = m4[r[u].x >> B_SHIFT];
#pragma unroll
    for (int u = 0; u < 8; ++u) {
      float w = __int_as_float(r[u].y);
      int a = (r[u].x & BMASK) * 5;
      LDSADD(&ac[a + 0], v[u].x * w);
      LDSADD(&ac[a + 1], v[u].y * w);
      LDSADD(&ac[a + 2], v[u].z * w);
      LDSADD(&ac[a + 3], v[u].w * w);
      LDSADD(&ac[a + 4], 1.0f);
    }
  }
  for (; i < e; i += NTHR) {
    int2 r = binned[i];
    float4 v = m4[r.x >> B_SHIFT];
    float w = __int_as_float(r.y);
    int a = (r.x & BMASK) * 5;
    LDSADD(&ac[a + 0], v.x * w);
    LDSADD(&ac[a + 1], v.y * w);
    LDSADD(&ac[a + 2], v.z * w);
    LDSADD(&ac[a + 3], v.w * w);
    LDSADD(&ac[a + 4], 1.0f);
  }
  __syncthreads();

  int node = (b << B_SHIFT) + tid;
  if (node < n) {
    float c = acc[0][tid * 5 + 4] + acc[1][tid * 5 + 4];
    if (c != 0.0f) {
      unsafeAtomicAdd(&sumBuf[(size_t)node * 4 + 0],
                      acc[0][tid * 5 + 0] + acc[1][tid * 5 + 0]);
      unsafeAtomicAdd(&sumBuf[(size_t)node * 4 + 1],
                      acc[0][tid * 5 + 1] + acc[1][tid * 5 + 1]);
      unsafeAtomicAdd(&sumBuf[(size_t)node * 4 + 2],
                      acc[0][tid * 5 + 2] + acc[1][tid * 5 + 2]);
      unsafeAtomicAdd(&sumBuf[(size_t)node * 4 + 3],
                      acc[0][tid * 5 + 3] + acc[1][tid * 5 + 3]);
      unsafeAtomicAdd(&cntBuf[node], c);
    }
  }
}

// fused GRU+LSTM+head; weights staged in LDS; jc loop kept ROLLED
// (full unroll was ~40KB of code -> I$ thrash / register bloat suspect)
__global__ __launch_bounds__(NTHR) void node_kernel2(
    const float* __restrict__ x, const float* __restrict__ sumBuf,
    const float* __restrict__ cntBuf,
    const float* __restrict__ h0, const float* __restrict__ c0,
    const float* __restrict__ gwi, const float* __restrict__ gwh,
    const float* __restrict__ gbi, const float* __restrict__ gbh,
    const float* __restrict__ lwi, const float* __restrict__ lwh,
    const float* __restrict__ lbi, const float* __restrict__ lbh,
    const float* __restrict__ linw, const float* __restrict__ linb,
    float* __restrict__ out, float* __restrict__ hout, float* __restrict__ cout,
    int n) {
  __shared__ float4 s_lwh[1024];   // [j*8+q], j<128, q<8
  __shared__ float4 s_lwi[128];    // [j]
  __shared__ float  s_lb[128];     // lbi[j]+lbh[j]
  __shared__ float  s_linw[32];
  __shared__ float  s_gwi[48], s_gwh[48], s_gbi[12], s_gbh[12];

  int tid = threadIdx.x;
  for (int k = tid; k < 4096; k += NTHR) ((float*)s_lwh)[k] = lwh[k];
  for (int k = tid; k < 512; k += NTHR) ((float*)s_lwi)[k] = lwi[k];
  if (tid < 128) s_lb[tid] = lbi[tid] + lbh[tid];
  if (tid < 32) s_linw[tid] = linw[tid];
  if (tid < 48) { s_gwi[tid] = gwi[tid]; s_gwh[tid] = gwh[tid]; }
  if (tid < 12) { s_gbi[tid] = gbi[tid]; s_gbh[tid] = gbh[tid]; }
  __syncthreads();

  int i = blockIdx.x * blockDim.x + tid;
  if (i >= n) return;

  float4 sv = reinterpret_cast<const float4*>(sumBuf)[i];
  float inv = 1.0f / fmaxf(cntBuf[i], 1.0f);
  float agg[4] = {sv.x * inv, sv.y * inv, sv.z * inv, sv.w * inv};
  float4 xv = reinterpret_cast<const float4*>(x)[i];
  float xa[4] = {xv.x, xv.y, xv.z, xv.w};

  // ---- GRUCell (gate order r,z,n)
  float hc[4];
#pragma unroll
  for (int c = 0; c < 4; ++c) {
    float gi_r = s_gbi[c],     gh_r = s_gbh[c];
    float gi_z = s_gbi[4 + c], gh_z = s_gbh[4 + c];
    float gi_n = s_gbi[8 + c], gh_n = s_gbh[8 + c];
#pragma unroll
    for (int k = 0; k < 4; ++k) {
      gi_r += agg[k] * s_gwi[c * 4 + k];       gh_r += xa[k] * s_gwh[c * 4 + k];
      gi_z += agg[k] * s_gwi[(4 + c) * 4 + k]; gh_z += xa[k] * s_gwh[(4 + c) * 4 + k];
      gi_n += agg[k] * s_gwi[(8 + c) * 4 + k]; gh_n += xa[k] * s_gwh[(8 + c) * 4 + k];
    }
    float r = sigf(gi_r + gh_r);
    float z = sigf(gi_z + gh_z);
    float nn = tanhfast(gi_n + r * gh_n);
    hc[c] = (1.0f - z) * nn + z * xa[c];
  }

  // ---- LSTM single step (gate order i,f,g,o)
  const float4* h04 = reinterpret_cast<const float4*>(h0) + (size_t)i * 8;
  const float4* c04 = reinterpret_cast<const float4*>(c0) + (size_t)i * 8;
  float hp[32];
#pragma unroll
  for (int q = 0; q < 8; ++q) {
    float4 hv = h04[q];
    hp[q * 4 + 0] = hv.x; hp[q * 4 + 1] = hv.y;
    hp[q * 4 + 2] = hv.z; hp[q * 4 + 3] = hv.w;
  }
  float oacc = linb[0];
  float4* hout4 = reinterpret_cast<float4*>(hout) + (size_t)i * 8;
  float4* cout4 = reinterpret_cast<float4*>(cout) + (size_t)i * 8;

#pragma unroll 1
  for (int jc = 0; jc < 8; ++jc) {
    float4 cpv = c04[jc];
    float cpa[4] = {cpv.x, cpv.y, cpv.z, cpv.w};
    float hn[4], cn[4];
#pragma unroll
    for (int jj = 0; jj < 4; ++jj) {
      int j = jc * 4 + jj;
      float gI = s_lb[j];
      float gF = s_lb[32 + j];
      float gG = s_lb[64 + j];
      float gO = s_lb[96 + j];
      float4 wi = s_lwi[j], wf = s_lwi[32 + j], wg = s_lwi[64 + j], wo = s_lwi[96 + j];
      gI += hc[0] * wi.x + hc[1] * wi.y + hc[2] * wi.z + hc[3] * wi.w;
      gF += hc[0] * wf.x + hc[1] * wf.y + hc[2] * wf.z + hc[3] * wf.w;
      gG += hc[0] * wg.x + hc[1] * wg.y + hc[2] * wg.z + hc[3] * wg.w;
      gO += hc[0] * wo.x + hc[1] * wo.y + hc[2] * wo.z + hc[3] * wo.w;
#pragma unroll
      for (int q = 0; q < 8; ++q) {
        float4 a = s_lwh[j * 8 + q];
        float4 b = s_lwh[(32 + j) * 8 + q];
        float4 g = s_lwh[(64 + j) * 8 + q];
        float4 o = s_lwh[(96 + j) * 8 + q];
        float p0 = hp[q * 4 + 0], p1 = hp[q * 4 + 1];
        float p2 = hp[q * 4 + 2], p3 = hp[q * 4 + 3];
        gI += p0 * a.x + p1 * a.y + p2 * a.z + p3 * a.w;
        gF += p0 * b.x + p1 * b.y + p2 * b.z + p3 * b.w;
        gG += p0 * g.x + p1 * g.y + p2 * g.z + p3 * g.w;
        gO += p0 * o.x + p1 * o.y + p2 * o.z + p3 * o.w;
      }
      float ig = sigf(gI), fg = sigf(gF), og = sigf(gO), gg = tanhfast(gG);
      float cnew = fg * cpa[jj] + ig * gg;
      float hnew = og * tanhfast(cnew);
      cn[jj] = cnew; hn[jj] = hnew;
      oacc += fmaxf(hnew, 0.0f) * s_linw[j];
    }
    hout4[jc] = make_float4(hn[0], hn[1], hn[2], hn[3]);
    cout4[jc] = make_float4(cn[0], cn[1], cn[2], cn[3]);
  }
  out[i] = oacc;
}

// ---------- fallback path (known correct, atomic-bound) ----------

__global__ void edge_kernel(const int* __restrict__ ei,
                            const float* __restrict__ ew,
                            const float* __restrict__ m,
                            float* __restrict__ summed,
                            float* __restrict__ cnt, int E) {
  int t = blockIdx.x * blockDim.x + threadIdx.x;
  int e0 = t * 4;
  const float4* m4 = reinterpret_cast<const float4*>(m);
  for (int e = e0; e < E && e < e0 + 4; ++e) {
    int s = ei[e], d = ei[E + e];
    float w = ew[e];
    float4 mv = m4[s];
    float* p = summed + 4ll * d;
    unsafeAtomicAdd(p + 0, mv.x * w);
    unsafeAtomicAdd(p + 1, mv.y * w);
    unsafeAtomicAdd(p + 2, mv.z * w);
    unsafeAtomicAdd(p + 3, mv.w * w);
    unsafeAtomicAdd(cnt + d, 1.0f);
  }
}

__global__ __launch_bounds__(NTHR) void node_kernel(
    const float* __restrict__ x, const float* __restrict__ summed,
    const float* __restrict__ cnt,
    const float* __restrict__ h0, const float* __restrict__ c0,
    const float* __restrict__ gwi, const float* __restrict__ gwh,
    const float* __restrict__ gbi, const float* __restrict__ gbh,
    const float* __restrict__ lwi, const float* __restrict__ lwh,
    const float* __restrict__ lbi, const float* __restrict__ lbh,
    const float* __restrict__ linw, const float* __restrict__ linb,
    float* __restrict__ out, float* __restrict__ hout, float* __restrict__ cout,
    int n) {
  int i = blockIdx.x * blockDim.x + threadIdx.x;
  if (i >= n) return;
  float4 sv = reinterpret_cast<const float4*>(summed)[i];
  float inv = 1.0f / fmaxf(cnt[i], 1.0f);
  float agg[4] = {sv.x * inv, sv.y * inv, sv.z * inv, sv.w * inv};
  float4 xv = reinterpret_cast<const float4*>(x)[i];
  float xa[4] = {xv.x, xv.y, xv.z, xv.w};
  float hc[4];
#pragma unroll
  for (int c = 0; c < 4; ++c) {
    float gi_r = gbi[c],     gh_r = gbh[c];
    float gi_z = gbi[4 + c], gh_z = gbh[4 + c];
    float gi_n = gbi[8 + c], gh_n = gbh[8 + c];
#pragma unroll
    for (int k = 0; k < 4; ++k) {
      gi_r += agg[k] * gwi[c * 4 + k];       gh_r += xa[k] * gwh[c * 4 + k];
      gi_z += agg[k] * gwi[(4 + c) * 4 + k]; gh_z += xa[k] * gwh[(4 + c) * 4 + k];
      gi_n += agg[k] * gwi[(8 + c) * 4 + k]; gh_n += xa[k] * gwh[(8 + c) * 4 + k];
    }
    float r = sigf(gi_r + gh_r);
    float z = sigf(gi_z + gh_z);
    float nn = tanhfast(gi_n + r * gh_n);
    hc[c] = (1.0f - z) * nn + z * xa[c];
  }
  const float4* h04 = reinterpret_cast<const float4*>(h0) + (size_t)i * 8;
  const float4* c04 = reinterpret_cast<const float4*>(c0) + (size_t)i * 8;
  float hp[32];
#pragma unroll
  for (int q = 0; q < 8; ++q) {
    float4 hv = h04[q];
    hp[q * 4 + 0] = hv.x; hp[q * 4 + 1] = hv.y;
    hp[q * 4 + 2] = hv.z; hp[q * 4 + 3] = hv.w;
  }
  const float4* wih4 = reinterpret_cast<const float4*>(lwi);
  const float4* whh4 = reinterpret_cast<const float4*>(lwh);
  float oacc = linb[0];
  float4* hout4 = reinterpret_cast<float4*>(hout) + (size_t)i * 8;
  float4* cout4 = reinterpret_cast<float4*>(cout) + (size_t)i * 8;
#pragma unroll 1
  for (int jc = 0; jc < 8; ++jc) {
    float4 cpv = c04[jc];
    float cpa[4] = {cpv.x, cpv.y, cpv.z, cpv.w};
    float hn[4], cn[4];
#pragma unroll
    for (int jj = 0; jj < 4; ++jj) {
      int j = jc * 4 + jj;
      float gI = lbi[j]      + lbh[j];
      float gF = lbi[32 + j] + lbh[32 + j];
      float gG = lbi[64 + j] + lbh[64 + j];
      float gO = lbi[96 + j] + lbh[96 + j];
      float4 wi = wih4[j], wf = wih4[32 + j], wg = wih4[64 + j], wo = wih4[96 + j];
      gI += hc[0] * wi.x + hc[1] * wi.y + hc[2] * wi.z + hc[3] * wi.w;
      gF += hc[0] * wf.x + hc[1] * wf.y + hc[2] * wf.z + hc[3] * wf.w;
      gG += hc[0] * wg.x + hc[1] * wg.y + hc[2] * wg.z + hc[3] * wg.w;
      gO += hc[0] * wo.x + hc[1] * wo.y + hc[2] * wo.z + hc[3] * wo.w;
#pragma unroll
      for (int q = 0; q < 8; ++q) {
        float4 a = whh4[j * 8 + q];
        float4 b = whh4[(32 + j) * 8 + q];
        float4 g = whh4[(64 + j) * 8 + q];
        float4 o = whh4[(96 + j) * 8 + q];
        float p0 = hp[q * 4 + 0], p1 = hp[q * 4 + 1];
        float p2 = hp[q * 4 + 2], p3 = hp[q * 4 + 3];
        gI += p0 * a.x + p1 * a.y + p2 * a.z + p3 * a.w;
        gF += p0 * b.x + p1 * b.y + p2 * b.z + p3 * b.w;
        gG += p0 * g.x + p1 * g.y + p2 * g.z + p3 * g.w;
        gO += p0 * o.x + p1 * o.y + p2 * o.z + p3 * o.w;
      }
      float ig = sigf(gI), fg = sigf(gF), og = sigf(gO), gg = tanhfast(gG);
      float cnew = fg * cpa[jj] + ig * gg;
      float hnew = og * tanhfast(cnew);
      cn[jj] = cnew; hn[jj] = hnew;
      oacc += fmaxf(hnew, 0.0f) * linw[j];
    }
    hout4[jc] = make_float4(hn[0], hn[1], hn[2], hn[3]);
    cout4[jc] = make_float4(cn[0], cn[1], cn[2], cn[3]);
  }
  out[i] = oacc;
}

extern "C" void kernel_launch(void* const* d_in, const int* in_sizes, int n_in,
                              void* d_out, int out_size, void* d_ws, size_t ws_size,
                              hipStream_t stream) {
  const float* x     = (const float*)d_in[0];
  const int*   ei    = (const int*)d_in[1];
  const float* ew    = (const float*)d_in[2];
  const float* h0    = (const float*)d_in[3];
  const float* c0    = (const float*)d_in[4];
  const float* convw = (const float*)d_in[5];
  const float* gwi   = (const float*)d_in[6];
  const float* gwh   = (const float*)d_in[7];
  const float* gbi   = (const float*)d_in[8];
  const float* gbh   = (const float*)d_in[9];
  const float* lwi   = (const float*)d_in[10];
  const float* lwh   = (const float*)d_in[11];
  const float* lbi   = (const float*)d_in[12];
  const float* lbh   = (const float*)d_in[13];
  const float* linw  = (const float*)d_in[14];
  const float* linb  = (const float*)d_in[15];

  int n = in_sizes[0] / 4;   // N nodes
  int E = in_sizes[1] / 2;   // edges

  float* out  = (float*)d_out;
  float* hout = out + n;
  float* cout = hout + (size_t)n * 32;

  int B = (n + BMASK) >> B_SHIFT;                    // buckets (<=1024 req'd)
  size_t need = (size_t)E * 8 + (size_t)n * 36 + ((size_t)3 * B + 2) * 4 + 64;

  if (B <= 1024 && ws_size >= need) {
    // ---- fast binned path ----
    int2*  binned = (int2*)d_ws;                     // E records
    float* m      = (float*)(binned + E);            // N*4
    float* sumBuf = m + (size_t)n * 4;               // N*4
    float* cntBuf = sumBuf + (size_t)n * 4;          // N
    int*   gCnt   = (int*)(cntBuf + n);              // B
    int*   start  = gCnt + B;                        // B+1
    int*   cursor = start + B + 1;                   // B

    hipMemsetAsync(gCnt, 0, (size_t)B * sizeof(int), stream);
    hipMemsetAsync(sumBuf, 0, (size_t)n * 5 * sizeof(float), stream);
    conv_m_kernel<<<(n + NTHR - 1) / NTHR, NTHR, 0, stream>>>(x, convw, m, n);

    int nbBlocks = (E + CHUNK - 1) / CHUNK;
    hist_kernel<<<nbBlocks, NTHR, 0, stream>>>(ei + E, E, B, gCnt);
    scan_kernel<<<1, 1024, 0, stream>>>(gCnt, B, start, cursor);
    bin_kernel<<<nbBlocks, NTHR, 0, stream>>>(ei, ew, E, B, cursor, binned);

    edge_agg_kernel<<<dim3(B, SEG), NTHR, 0, stream>>>(m, binned, start,
                                                       sumBuf, cntBuf, n);
    node_kernel2<<<(n + NTHR - 1) / NTHR, NTHR, 0, stream>>>(
        x, sumBuf, cntBuf, h0, c0,
        gwi, gwh, gbi, gbh, lwi, lwh, lbi, lbh, linw, linb,
        out, hout, cout, n);
  } else {
    // ---- fallback: global-atomic scatter (known correct) ----
    float* m      = (float*)d_ws;
    float* summed = m + (size_t)n * 4;
    float* cntp   = summed + (size_t)n * 4;
    hipMemsetAsync(summed, 0, (size_t)n * 5 * sizeof(float), stream);
    conv_m_kernel<<<(n + NTHR - 1) / NTHR, NTHR, 0, stream>>>(x, convw, m, n);
    int et = (E + 3) / 4;
    edge_kernel<<<(et + NTHR - 1) / NTHR, NTHR, 0, stream>>>(ei, ew, m, summed, cntp, E);
    node_kernel<<<(n + NTHR - 1) / NTHR, NTHR, 0, stream>>>(
        x, summed, cntp, h0, c0,
        gwi, gwh, gbi, gbh, lwi, lwh, lbi, lbh, linw, linb,
        out, hout, cout, n);
  }
}